// Round 3
// baseline (8733.982 us; speedup 1.0000x reference)
//
#include <hip/hip_runtime.h>
#include <stdint.h>

#define BATCH_N   131072
#define HID       256
#define SPIKE_DIM 128
#define COORD_DIM 64
#define IN_DIM    192
#define STEPS     25
#define TILE      64
#define BLOCK     512
#define KCHUNK    24

typedef float f4 __attribute__((ext_vector_type(4)));

// ws layout (floats)
#define W0T_OFF 0                        // [IN_DIM][HID]     49152
#define W1T_OFF (IN_DIM*HID)             // [HID][HID]        65536
#define WOT_OFF (W1T_OFF + HID*HID)      // [HID][COORD_DIM]  16384

__global__ __launch_bounds__(256)
void prep_kernel(const float* __restrict__ W0,
                 const float* __restrict__ W1,
                 const float* __restrict__ Wout,
                 float* __restrict__ ws) {
  int idx = blockIdx.x * 256 + threadIdx.x;
  if (idx < IN_DIM*HID) {               // W0T[j][i] = W0[i][j]
    int j = idx >> 8, i = idx & 255;
    ws[W0T_OFF + idx] = W0[i*IN_DIM + j];
  }
  int i1 = idx - IN_DIM*HID;            // W1T[j][i] = W1[i][j]
  if (i1 >= 0 && i1 < HID*HID) {
    int j = i1 >> 8, i = i1 & 255;
    ws[W1T_OFF + i1] = W1[i*HID + j];
  }
  int i2 = idx - (IN_DIM*HID + HID*HID);// WoT[k][c] = Wout[128+c][k]
  if (i2 >= 0 && i2 < HID*COORD_DIM) {
    int k = i2 >> 6, c = i2 & 63;
    ws[WOT_OFF + i2] = Wout[(SPIKE_DIM + c)*HID + k];
  }
}

__global__ __launch_bounds__(BLOCK)
void snn_kernel(const float* __restrict__ spk,
                const float* __restrict__ crd,
                const float* __restrict__ b0,
                const float* __restrict__ b1,
                const float* __restrict__ bout,
                const float* __restrict__ ws,
                float* __restrict__ out) {
  __shared__ float xs[TILE*IN_DIM];     // 12288 f = 48 KB
  __shared__ float wch[KCHUNK*HID];     //  6144 f = 24 KB (72 KB -> 2 blocks/CU)

  const int tid  = threadIdx.x;
  const int lane = tid & 63;
  const int wv   = tid >> 6;            // wave 0..7
  const int e0   = blockIdx.x * TILE;
  const int i4   = lane * 4;            // this lane's 4 neurons: i4..i4+3
  const int eb   = wv * 8;              // this wave's 8 elements (local)

  // ---- stage x tile (spikes || coords) into LDS, nontemporal f4 loads ----
  {
    const f4* sp4 = (const f4*)(spk + (size_t)e0 * SPIKE_DIM);
    for (int t = tid; t < TILE*SPIKE_DIM/4; t += BLOCK) {
      int e = t >> 5, j = (t & 31) * 4;          // 32 f4 per spike row
      *(f4*)&xs[e*IN_DIM + j] = __builtin_nontemporal_load(&sp4[t]);
    }
    const f4* cr4 = (const f4*)(crd + (size_t)e0 * COORD_DIM);
    for (int t = tid; t < TILE*COORD_DIM/4; t += BLOCK) {
      int e = t >> 4, j = (t & 15) * 4;          // 16 f4 per coord row
      *(f4*)&xs[e*IN_DIM + SPIKE_DIM + j] = __builtin_nontemporal_load(&cr4[t]);
    }
  }

  // ---- Phase A: c0 = x @ W0^T (thread: 8 elems x 4 outputs, regs only) ----
  float acc[8][4];
  #pragma unroll
  for (int ee = 0; ee < 8; ++ee)
    acc[ee][0] = acc[ee][1] = acc[ee][2] = acc[ee][3] = 0.0f;

  const float* W0T = ws + W0T_OFF;
  for (int kc = 0; kc < IN_DIM/KCHUNK; ++kc) {
    __syncthreads();
    const f4* src = (const f4*)(W0T + kc*KCHUNK*HID);
    for (int t = tid; t < KCHUNK*HID/4; t += BLOCK)
      *(f4*)&wch[t*4] = src[t];
    __syncthreads();
    for (int j = 0; j < KCHUNK; ++j) {
      f4 w = *(const f4*)&wch[j*HID + i4];
      int jj = kc*KCHUNK + j;
      #pragma unroll
      for (int ee = 0; ee < 8; ++ee) {
        float xv = xs[(eb+ee)*IN_DIM + jj];      // wave-uniform -> LDS broadcast
        acc[ee][0] += xv * w.x;
        acc[ee][1] += xv * w.y;
        acc[ee][2] += xv * w.z;
        acc[ee][3] += xv * w.w;
      }
    }
  }

  // ---- Phase B: per-element bound check, fast path or honest sim ----
  // Theory (rigorous incl. fp32 rounding):
  //  * layer-0 neuron with c0 < 0.96 can never spike (v<=0.97 invariant).
  //  * "active" set = {c0 >= 0.96}; any neuron that ever fires is in it.
  //  * c1_t <= b1_i + sum_{j in active} max(W1T[j][i],0) = bound_i.
  //    If bound_i < 0.98 for all i -> v1 < 0.99 forever -> s1 == 0 ->
  //    next_action = 0 exactly, next_coords = b_out exactly.
  const float* W1T = ws + W1T_OFF;
  const float* WoT = ws + WOT_OFF;
  f4 b0v = *(const f4*)&b0[i4];
  f4 b1v = *(const f4*)&b1[i4];
  float bc = bout[SPIKE_DIM + lane];

  #pragma unroll
  for (int ee = 0; ee < 8; ++ee) {
    const int e = e0 + eb + ee;
    f4 c0;
    c0.x = acc[ee][0] + b0v.x;
    c0.y = acc[ee][1] + b0v.y;
    c0.z = acc[ee][2] + b0v.z;
    c0.w = acc[ee][3] + b0v.w;

    // active-set masks (conservative threshold)
    unsigned long long a0 = __ballot(c0.x >= 0.96f);
    unsigned long long a1 = __ballot(c0.y >= 0.96f);
    unsigned long long a2 = __ballot(c0.z >= 0.96f);
    unsigned long long a3 = __ballot(c0.w >= 0.96f);

    // bound_i = b1_i + sum over active cols of positive parts
    f4 bnd = b1v;
    unsigned long long mm;
    #define BPROCQ(MASK, Q)                                   \
      mm = (MASK);                                            \
      while (mm) {                                            \
        int l = __builtin_ctzll(mm); mm &= mm - 1;            \
        f4 wv_ = *(const f4*)&W1T[(l*4 + (Q))*HID + i4];      \
        bnd.x += fmaxf(wv_.x, 0.f);                           \
        bnd.y += fmaxf(wv_.y, 0.f);                           \
        bnd.z += fmaxf(wv_.z, 0.f);                           \
        bnd.w += fmaxf(wv_.w, 0.f);                           \
      }
    BPROCQ(a0, 0)
    BPROCQ(a1, 1)
    BPROCQ(a2, 2)
    BPROCQ(a3, 3)
    #undef BPROCQ

    bool threat = (bnd.x >= 0.98f) | (bnd.y >= 0.98f) |
                  (bnd.z >= 0.98f) | (bnd.w >= 0.98f);
    unsigned long long tm = __ballot(threat);

    if (tm == 0ull) {
      // ---- fast path: provably no layer-1 spikes ----
      f4 z; z.x = z.y = z.z = z.w = 0.f;
      __builtin_nontemporal_store(z, (f4*)&out[(size_t)e*HID + i4]);
      __builtin_nontemporal_store(bc,
          &out[(size_t)BATCH_N*HID + (size_t)e*COORD_DIM + lane]);
    } else {
      // ---- slow path: honest 25-step simulation (round-2 verbatim) ----
      const float c0x = c0.x, c0y = c0.y, c0z = c0.z, c0w = c0.w;
      float v0x=0.f, v0y=0.f, v0z=0.f, v0w=0.f;
      float v1x=0.f, v1y=0.f, v1z=0.f, v1w=0.f;
      float s1x=0.f, s1y=0.f, s1z=0.f, s1w=0.f;

      for (int t = 0; t < STEPS; ++t) {
        bool sp;
        unsigned long long m0, m1, m2, m3;
        v0x = __fmul_rn(0.7f, v0x) + __fmul_rn(0.3f, c0x);
        sp = (v0x >= 1.0f); m0 = __ballot(sp); if (sp) v0x = 0.f;
        v0y = __fmul_rn(0.7f, v0y) + __fmul_rn(0.3f, c0y);
        sp = (v0y >= 1.0f); m1 = __ballot(sp); if (sp) v0y = 0.f;
        v0z = __fmul_rn(0.7f, v0z) + __fmul_rn(0.3f, c0z);
        sp = (v0z >= 1.0f); m2 = __ballot(sp); if (sp) v0z = 0.f;
        v0w = __fmul_rn(0.7f, v0w) + __fmul_rn(0.3f, c0w);
        sp = (v0w >= 1.0f); m3 = __ballot(sp); if (sp) v0w = 0.f;

        float c1x = b1v.x, c1y = b1v.y, c1z = b1v.z, c1w = b1v.w;
        f4 wcur; wcur.x = wcur.y = wcur.z = wcur.w = 0.f;
        int have = 0;
        #define PROCQ(MASK, Q)                                                  \
          mm = (MASK);                                                          \
          while (mm) {                                                          \
            int l = __builtin_ctzll(mm); mm &= mm - 1;                          \
            f4 wn = *(const f4*)&W1T[(l*4 + (Q))*HID + i4];                     \
            if (have) { c1x += wcur.x; c1y += wcur.y; c1z += wcur.z; c1w += wcur.w; } \
            wcur = wn; have = 1;                                                \
          }
        PROCQ(m0, 0)
        PROCQ(m1, 1)
        PROCQ(m2, 2)
        PROCQ(m3, 3)
        #undef PROCQ
        if (have) { c1x += wcur.x; c1y += wcur.y; c1z += wcur.z; c1w += wcur.w; }

        v1x = __fmul_rn(0.7f, v1x) + __fmul_rn(0.3f, c1x);
        sp = (v1x >= 1.0f); s1x = sp ? 1.f : 0.f; if (sp) v1x = 0.f;
        v1y = __fmul_rn(0.7f, v1y) + __fmul_rn(0.3f, c1y);
        sp = (v1y >= 1.0f); s1y = sp ? 1.f : 0.f; if (sp) v1y = 0.f;
        v1z = __fmul_rn(0.7f, v1z) + __fmul_rn(0.3f, c1z);
        sp = (v1z >= 1.0f); s1z = sp ? 1.f : 0.f; if (sp) v1z = 0.f;
        v1w = __fmul_rn(0.7f, v1w) + __fmul_rn(0.3f, c1w);
        sp = (v1w >= 1.0f); s1w = sp ? 1.f : 0.f; if (sp) v1w = 0.f;
      }

      f4 res; res.x = s1x; res.y = s1y; res.z = s1z; res.w = s1w;
      __builtin_nontemporal_store(res, (f4*)&out[(size_t)e*HID + i4]);

      unsigned long long f0 = __ballot(s1x > 0.5f);
      unsigned long long f1 = __ballot(s1y > 0.5f);
      unsigned long long f2 = __ballot(s1z > 0.5f);
      unsigned long long f3 = __ballot(s1w > 0.5f);
      float cacc = bc;
      #define CPROCQ(MASK, Q)                                 \
        mm = (MASK);                                          \
        while (mm) {                                          \
          int l = __builtin_ctzll(mm); mm &= mm - 1;          \
          cacc += WoT[(l*4 + (Q))*COORD_DIM + lane];          \
        }
      CPROCQ(f0, 0)
      CPROCQ(f1, 1)
      CPROCQ(f2, 2)
      CPROCQ(f3, 3)
      #undef CPROCQ
      __builtin_nontemporal_store(cacc,
          &out[(size_t)BATCH_N*HID + (size_t)e*COORD_DIM + lane]);
    }
  }
}

extern "C" void kernel_launch(void* const* d_in, const int* in_sizes, int n_in,
                              void* d_out, int out_size, void* d_ws, size_t ws_size,
                              hipStream_t stream) {
  (void)in_sizes; (void)n_in; (void)out_size; (void)ws_size;
  const float* spk = (const float*)d_in[0];
  const float* crd = (const float*)d_in[1];
  const float* W0  = (const float*)d_in[2];
  const float* b0  = (const float*)d_in[3];
  const float* W1  = (const float*)d_in[4];
  const float* b1  = (const float*)d_in[5];
  const float* Wo  = (const float*)d_in[6];
  const float* bo  = (const float*)d_in[7];
  float* ws  = (float*)d_ws;
  float* out = (float*)d_out;

  hipLaunchKernelGGL(prep_kernel, dim3(512), dim3(256), 0, stream, W0, W1, Wo, ws);
  hipLaunchKernelGGL(snn_kernel, dim3(BATCH_N/TILE), dim3(BLOCK), 0, stream,
                     spk, crd, b0, b1, bo, ws, out);
}

// Round 4
// 392.242 us; speedup vs baseline: 22.2668x; 22.2668x over previous
//
#include <hip/hip_runtime.h>
#include <stdint.h>

#define BATCH_N   131072
#define HID       256
#define SPIKE_DIM 128
#define COORD_DIM 64
#define IN_DIM    192
#define STEPS     25
#define TILE      32
#define BLOCK     512
#define KCHUNK    24

typedef float f4 __attribute__((ext_vector_type(4)));

// ws layout (floats)
#define W0T_OFF 0                        // [IN_DIM][HID]     49152
#define W1T_OFF (IN_DIM*HID)             // [HID][HID]        65536
#define WOT_OFF (W1T_OFF + HID*HID)      // [HID][COORD_DIM]  16384

__global__ __launch_bounds__(256)
void prep_kernel(const float* __restrict__ W0,
                 const float* __restrict__ W1,
                 const float* __restrict__ Wout,
                 float* __restrict__ ws) {
  int idx = blockIdx.x * 256 + threadIdx.x;
  if (idx < IN_DIM*HID) {               // W0T[j][i] = W0[i][j]
    int j = idx >> 8, i = idx & 255;
    ws[W0T_OFF + idx] = W0[i*IN_DIM + j];
  }
  int i1 = idx - IN_DIM*HID;            // W1T[j][i] = W1[i][j]
  if (i1 >= 0 && i1 < HID*HID) {
    int j = i1 >> 8, i = i1 & 255;
    ws[W1T_OFF + i1] = W1[i*HID + j];
  }
  int i2 = idx - (IN_DIM*HID + HID*HID);// WoT[k][c] = Wout[128+c][k]
  if (i2 >= 0 && i2 < HID*COORD_DIM) {
    int k = i2 >> 6, c = i2 & 63;
    ws[WOT_OFF + i2] = Wout[(SPIKE_DIM + c)*HID + k];
  }
}

__global__ __launch_bounds__(BLOCK)
void snn_kernel(const float* __restrict__ spk,
                const float* __restrict__ crd,
                const float* __restrict__ b0,
                const float* __restrict__ b1,
                const float* __restrict__ bout,
                const float* __restrict__ ws,
                float* __restrict__ out) {
  // 48 KB LDS -> 3 blocks/CU.
  // Phase A view: xs[TILE][IN_DIM] + wch[KCHUNK][HID]
  // Phase B view: c0s[TILE][HID] aliased on top (behind __syncthreads()).
  // NOTE (round-3 lesson): acc[] MUST die before phase B (dump to LDS with
  // compile-time indices). Carrying a private array into the big phase-B
  // body makes the allocator spill it to scratch -> 22 GB phantom traffic.
  __shared__ float smem[TILE*IN_DIM + KCHUNK*HID];
  float* xs  = smem;
  float* wch = smem + TILE*IN_DIM;
  float* c0s = smem;

  const int tid  = threadIdx.x;
  const int lane = tid & 63;
  const int wv   = tid >> 6;            // wave 0..7
  const int e0   = blockIdx.x * TILE;
  const int i4   = lane * 4;            // this lane's 4 neurons: i4..i4+3
  const int eb   = wv * 4;              // this wave's 4 elements (local)

  // ---- stage x tile (spikes || coords) into LDS, nontemporal f4 loads ----
  {
    const f4* sp4 = (const f4*)(spk + (size_t)e0 * SPIKE_DIM);
    for (int t = tid; t < TILE*SPIKE_DIM/4; t += BLOCK) {
      int e = t >> 5, j = (t & 31) * 4;          // 32 f4 per spike row
      *(f4*)&xs[e*IN_DIM + j] = __builtin_nontemporal_load(&sp4[t]);
    }
    const f4* cr4 = (const f4*)(crd + (size_t)e0 * COORD_DIM);
    for (int t = tid; t < TILE*COORD_DIM/4; t += BLOCK) {
      int e = t >> 4, j = (t & 15) * 4;          // 16 f4 per coord row
      *(f4*)&xs[e*IN_DIM + SPIKE_DIM + j] = __builtin_nontemporal_load(&cr4[t]);
    }
  }

  // ---- Phase A: c0 = x @ W0^T (thread: 4 elems x 4 outputs, regs only) ----
  float acc[4][4];
  #pragma unroll
  for (int ee = 0; ee < 4; ++ee)
    acc[ee][0] = acc[ee][1] = acc[ee][2] = acc[ee][3] = 0.0f;

  const float* W0T = ws + W0T_OFF;
  for (int kc = 0; kc < IN_DIM/KCHUNK; ++kc) {
    __syncthreads();
    const f4* src = (const f4*)(W0T + kc*KCHUNK*HID);
    for (int t = tid; t < KCHUNK*HID/4; t += BLOCK)
      *(f4*)&wch[t*4] = src[t];
    __syncthreads();
    for (int j = 0; j < KCHUNK; ++j) {
      f4 w = *(const f4*)&wch[j*HID + i4];
      int jj = kc*KCHUNK + j;
      #pragma unroll
      for (int ee = 0; ee < 4; ++ee) {
        float xv = xs[(eb+ee)*IN_DIM + jj];      // wave-uniform -> LDS broadcast
        acc[ee][0] += xv * w.x;
        acc[ee][1] += xv * w.y;
        acc[ee][2] += xv * w.z;
        acc[ee][3] += xv * w.w;
      }
    }
  }

  // ---- dump c0 (+bias) to LDS with compile-time indices (kills acc) ----
  f4 b0v = *(const f4*)&b0[i4];
  f4 b1v = *(const f4*)&b1[i4];
  float bc = bout[SPIKE_DIM + lane];
  __syncthreads();
  #pragma unroll
  for (int ee = 0; ee < 4; ++ee) {
    f4 c;
    c.x = acc[ee][0] + b0v.x;
    c.y = acc[ee][1] + b0v.y;
    c.z = acc[ee][2] + b0v.z;
    c.w = acc[ee][3] + b0v.w;
    *(f4*)&c0s[(eb+ee)*HID + i4] = c;
  }
  __syncthreads();

  // ---- Phase B: per-element bound check -> fast path or honest sim ----
  // Rigorous (incl. fp32 rounding):
  //  * layer-0 neuron with c0 < 0.96 can never spike (v <= 0.97 invariant).
  //  * active set = {c0 >= 0.96}; any neuron that ever fires is in it.
  //  * c1_t <= b1_i + sum_{j active} max(W1T[j][i],0) = bound_i. If all
  //    bound_i < 0.98 -> v1 < 0.99 forever -> s1 == 0 -> next_action = 0
  //    exactly and next_coords = b_out exactly.
  const float* W1T = ws + W1T_OFF;
  const float* WoT = ws + WOT_OFF;

  for (int ee = 0; ee < 4; ++ee) {
    const int e = e0 + eb + ee;
    f4 c0 = *(const f4*)&c0s[(eb+ee)*HID + i4];

    unsigned long long a0 = __ballot(c0.x >= 0.96f);
    unsigned long long a1 = __ballot(c0.y >= 0.96f);
    unsigned long long a2 = __ballot(c0.z >= 0.96f);
    unsigned long long a3 = __ballot(c0.w >= 0.96f);

    f4 bnd = b1v;
    unsigned long long mm;
    #define BPROCQ(MASK, Q)                                   \
      mm = (MASK);                                            \
      while (mm) {                                            \
        int l = __builtin_ctzll(mm); mm &= mm - 1;            \
        f4 wv_ = *(const f4*)&W1T[(l*4 + (Q))*HID + i4];      \
        bnd.x += fmaxf(wv_.x, 0.f);                           \
        bnd.y += fmaxf(wv_.y, 0.f);                           \
        bnd.z += fmaxf(wv_.z, 0.f);                           \
        bnd.w += fmaxf(wv_.w, 0.f);                           \
      }
    BPROCQ(a0, 0)
    BPROCQ(a1, 1)
    BPROCQ(a2, 2)
    BPROCQ(a3, 3)
    #undef BPROCQ

    bool threat = (bnd.x >= 0.98f) | (bnd.y >= 0.98f) |
                  (bnd.z >= 0.98f) | (bnd.w >= 0.98f);

    if (__ballot(threat) == 0ull) {
      // fast path: provably no layer-1 spikes
      f4 z; z.x = z.y = z.z = z.w = 0.f;
      __builtin_nontemporal_store(z, (f4*)&out[(size_t)e*HID + i4]);
      __builtin_nontemporal_store(bc,
          &out[(size_t)BATCH_N*HID + (size_t)e*COORD_DIM + lane]);
    } else {
      // slow path: honest 25-step simulation (round-2 verbatim, exact)
      const float c0x = c0.x, c0y = c0.y, c0z = c0.z, c0w = c0.w;
      float v0x=0.f, v0y=0.f, v0z=0.f, v0w=0.f;
      float v1x=0.f, v1y=0.f, v1z=0.f, v1w=0.f;
      float s1x=0.f, s1y=0.f, s1z=0.f, s1w=0.f;

      for (int t = 0; t < STEPS; ++t) {
        bool sp;
        unsigned long long m0, m1, m2, m3;
        v0x = __fmul_rn(0.7f, v0x) + __fmul_rn(0.3f, c0x);
        sp = (v0x >= 1.0f); m0 = __ballot(sp); if (sp) v0x = 0.f;
        v0y = __fmul_rn(0.7f, v0y) + __fmul_rn(0.3f, c0y);
        sp = (v0y >= 1.0f); m1 = __ballot(sp); if (sp) v0y = 0.f;
        v0z = __fmul_rn(0.7f, v0z) + __fmul_rn(0.3f, c0z);
        sp = (v0z >= 1.0f); m2 = __ballot(sp); if (sp) v0z = 0.f;
        v0w = __fmul_rn(0.7f, v0w) + __fmul_rn(0.3f, c0w);
        sp = (v0w >= 1.0f); m3 = __ballot(sp); if (sp) v0w = 0.f;

        float c1x = b1v.x, c1y = b1v.y, c1z = b1v.z, c1w = b1v.w;
        f4 wcur; wcur.x = wcur.y = wcur.z = wcur.w = 0.f;
        int have = 0;
        #define PROCQ(MASK, Q)                                                  \
          mm = (MASK);                                                          \
          while (mm) {                                                          \
            int l = __builtin_ctzll(mm); mm &= mm - 1;                          \
            f4 wn = *(const f4*)&W1T[(l*4 + (Q))*HID + i4];                     \
            if (have) { c1x += wcur.x; c1y += wcur.y; c1z += wcur.z; c1w += wcur.w; } \
            wcur = wn; have = 1;                                                \
          }
        PROCQ(m0, 0)
        PROCQ(m1, 1)
        PROCQ(m2, 2)
        PROCQ(m3, 3)
        #undef PROCQ
        if (have) { c1x += wcur.x; c1y += wcur.y; c1z += wcur.z; c1w += wcur.w; }

        v1x = __fmul_rn(0.7f, v1x) + __fmul_rn(0.3f, c1x);
        sp = (v1x >= 1.0f); s1x = sp ? 1.f : 0.f; if (sp) v1x = 0.f;
        v1y = __fmul_rn(0.7f, v1y) + __fmul_rn(0.3f, c1y);
        sp = (v1y >= 1.0f); s1y = sp ? 1.f : 0.f; if (sp) v1y = 0.f;
        v1z = __fmul_rn(0.7f, v1z) + __fmul_rn(0.3f, c1z);
        sp = (v1z >= 1.0f); s1z = sp ? 1.f : 0.f; if (sp) v1z = 0.f;
        v1w = __fmul_rn(0.7f, v1w) + __fmul_rn(0.3f, c1w);
        sp = (v1w >= 1.0f); s1w = sp ? 1.f : 0.f; if (sp) v1w = 0.f;
      }

      f4 res; res.x = s1x; res.y = s1y; res.z = s1z; res.w = s1w;
      __builtin_nontemporal_store(res, (f4*)&out[(size_t)e*HID + i4]);

      unsigned long long f0 = __ballot(s1x > 0.5f);
      unsigned long long f1 = __ballot(s1y > 0.5f);
      unsigned long long f2 = __ballot(s1z > 0.5f);
      unsigned long long f3 = __ballot(s1w > 0.5f);
      float cacc = bc;
      #define CPROCQ(MASK, Q)                                 \
        mm = (MASK);                                          \
        while (mm) {                                          \
          int l = __builtin_ctzll(mm); mm &= mm - 1;          \
          cacc += WoT[(l*4 + (Q))*COORD_DIM + lane];          \
        }
      CPROCQ(f0, 0)
      CPROCQ(f1, 1)
      CPROCQ(f2, 2)
      CPROCQ(f3, 3)
      #undef CPROCQ
      __builtin_nontemporal_store(cacc,
          &out[(size_t)BATCH_N*HID + (size_t)e*COORD_DIM + lane]);
    }
  }
}

extern "C" void kernel_launch(void* const* d_in, const int* in_sizes, int n_in,
                              void* d_out, int out_size, void* d_ws, size_t ws_size,
                              hipStream_t stream) {
  (void)in_sizes; (void)n_in; (void)out_size; (void)ws_size;
  const float* spk = (const float*)d_in[0];
  const float* crd = (const float*)d_in[1];
  const float* W0  = (const float*)d_in[2];
  const float* b0  = (const float*)d_in[3];
  const float* W1  = (const float*)d_in[4];
  const float* b1  = (const float*)d_in[5];
  const float* Wo  = (const float*)d_in[6];
  const float* bo  = (const float*)d_in[7];
  float* ws  = (float*)d_ws;
  float* out = (float*)d_out;

  hipLaunchKernelGGL(prep_kernel, dim3(512), dim3(256), 0, stream, W0, W1, Wo, ws);
  hipLaunchKernelGGL(snn_kernel, dim3(BATCH_N/TILE), dim3(BLOCK), 0, stream,
                     spk, crd, b0, b1, bo, ws, out);
}

// Round 5
// 365.549 us; speedup vs baseline: 23.8928x; 1.0730x over previous
//
#include <hip/hip_runtime.h>
#include <stdint.h>

#define BATCH_N   131072
#define HID       256
#define SPIKE_DIM 128
#define COORD_DIM 64
#define IN_DIM    192
#define STEPS     25
#define TILE      64
#define BLOCK     512

typedef float f4  __attribute__((ext_vector_type(4)));
typedef short bf8 __attribute__((ext_vector_type(8)));
typedef unsigned short us4 __attribute__((ext_vector_type(4)));

// ws layout:
//   W0b  [256][192] bf16   at byte 0        (49152 ushorts = 96 KB)
//   W1T  [256][256] fp32   at float 24576   (65536 floats)
//   WoT  [256][64]  fp32   at float 90112   (16384 floats)
#define W1T_OFF 24576
#define WOT_OFF 90112

static __device__ __forceinline__ unsigned short f2bf(float f) {
  union { float f; unsigned u; } v; v.f = f;
  unsigned r = v.u + 0x7FFF + ((v.u >> 16) & 1);   // RNE
  return (unsigned short)(r >> 16);
}
static __device__ __forceinline__ float bf2f(unsigned short h) {
  union { unsigned u; float f; } v; v.u = ((unsigned)h) << 16; return v.f;
}

__global__ __launch_bounds__(256)
void prep_kernel(const float* __restrict__ W0,
                 const float* __restrict__ W1,
                 const float* __restrict__ Wout,
                 float* __restrict__ ws) {
  int idx = blockIdx.x * 256 + threadIdx.x;
  if (idx < HID*IN_DIM) {               // W0b elementwise (row-major, k-contig)
    ((unsigned short*)ws)[idx] = f2bf(W0[idx]);
  }
  int i1 = idx - HID*IN_DIM;            // W1T[j][i] = W1[i][j]
  if (i1 >= 0 && i1 < HID*HID) {
    int j = i1 >> 8, i = i1 & 255;
    ws[W1T_OFF + i1] = W1[i*HID + j];
  }
  int i2 = idx - (HID*IN_DIM + HID*HID);// WoT[k][c] = Wout[128+c][k]
  if (i2 >= 0 && i2 < HID*COORD_DIM) {
    int k = i2 >> 6, c = i2 & 63;
    ws[WOT_OFF + i2] = Wout[(SPIKE_DIM + c)*HID + k];
  }
}

__global__ __launch_bounds__(BLOCK)
void snn_kernel(const float* __restrict__ spk,
                const float* __restrict__ crd,
                const float* __restrict__ W0,
                const float* __restrict__ b0,
                const float* __restrict__ b1,
                const float* __restrict__ bout,
                const float* __restrict__ ws,
                float* __restrict__ out) {
  // LDS union (33792 B -> 4 blocks/CU by LDS):
  //   Phase A: xb[64][200] bf16  (x staged, stride 200 -> 16B-aligned frags,
  //            bank stride 100 dw = 2-way only)
  //   Phase B: c0s[64][264] bf16 (aliased, behind barriers; acc dies here --
  //            round-3 lesson: no private array may live into phase B)
  __shared__ unsigned short sbuf[TILE*264];
  unsigned short* xb  = sbuf;           // stride 200
  unsigned short* c0s = sbuf;           // stride 264

  const int tid  = threadIdx.x;
  const int lane = tid & 63;
  const int wv   = tid >> 6;            // wave 0..7
  const int quad = lane >> 4;
  const int l15  = lane & 15;
  const int e0   = blockIdx.x * TILE;
  const int i4   = lane * 4;            // phase-B: this lane's 4 neurons

  // ---- stage x tile as bf16 into LDS ----
  {
    const f4* sp4 = (const f4*)(spk + (size_t)e0 * SPIKE_DIM);
    for (int t = tid; t < TILE*SPIKE_DIM/4; t += BLOCK) {
      int e = t >> 5, j = (t & 31) * 4;
      f4 v = __builtin_nontemporal_load(&sp4[t]);
      us4 h; h.x = f2bf(v.x); h.y = f2bf(v.y); h.z = f2bf(v.z); h.w = f2bf(v.w);
      *(us4*)&xb[e*200 + j] = h;
    }
    const f4* cr4 = (const f4*)(crd + (size_t)e0 * COORD_DIM);
    for (int t = tid; t < TILE*COORD_DIM/4; t += BLOCK) {
      int e = t >> 4, j = SPIKE_DIM + (t & 15) * 4;
      f4 v = __builtin_nontemporal_load(&cr4[t]);
      us4 h; h.x = f2bf(v.x); h.y = f2bf(v.y); h.z = f2bf(v.z); h.w = f2bf(v.w);
      *(us4*)&xb[e*200 + j] = h;
    }
  }
  __syncthreads();

  // ---- Phase A: c0 ~= x @ W0^T via bf16 MFMA (16x16x32) ----
  // wave tile: 16 elements (msub) x 128 neurons (nhalf, 8 subtiles of 16)
  const int msub  = wv >> 1;
  const int nhalf = wv & 1;
  const unsigned short* W0b = (const unsigned short*)ws;  // [256][192]

  f4 acc[8];
  #pragma unroll
  for (int n = 0; n < 8; ++n) { acc[n].x = acc[n].y = acc[n].z = acc[n].w = 0.f; }

  #pragma unroll
  for (int kc = 0; kc < IN_DIM/32; ++kc) {
    bf8 a = *(const bf8*)&xb[(msub*16 + l15)*200 + kc*32 + quad*8];
    #pragma unroll
    for (int n = 0; n < 8; ++n) {
      bf8 b = *(const bf8*)&W0b[(size_t)(nhalf*128 + n*16 + l15)*IN_DIM + kc*32 + quad*8];
      acc[n] = __builtin_amdgcn_mfma_f32_16x16x32_bf16(a, b, acc[n], 0, 0, 0);
    }
  }

  // ---- dump c0(+b0) as bf16 to LDS; C/D layout: col=lane&15, row=quad*4+reg
  __syncthreads();
  {
    const int erow = msub*16 + quad*4;
    #pragma unroll
    for (int n = 0; n < 8; ++n) {
      const int neuron = nhalf*128 + n*16 + l15;
      const float bias = b0[neuron];
      c0s[(erow+0)*264 + neuron] = f2bf(acc[n].x + bias);
      c0s[(erow+1)*264 + neuron] = f2bf(acc[n].y + bias);
      c0s[(erow+2)*264 + neuron] = f2bf(acc[n].z + bias);
      c0s[(erow+3)*264 + neuron] = f2bf(acc[n].w + bias);
    }
  }
  __syncthreads();

  // ---- Phase B: per-element bound check -> fast path or exact slow path ----
  // Rigor: a layer-0 neuron that ever spikes has exact c0 >= 0.96; MFMA+bf16
  // error <= ~0.055 -> mask threshold 0.90 gives a superset. bound_i = b1_i +
  // sum over superset of max(W1T,0) >= any c1_t. All bound_i < 0.98 -> s1==0
  // -> outputs (0, b_out) EXACT. Else: recompute c0 exactly (serial FMA, j
  // ascending == round-2's v_fmac chain) and run the verbatim honest sim.
  const float* W1T = ws + W1T_OFF;
  const float* WoT = ws + WOT_OFF;
  f4 b0v = *(const f4*)&b0[i4];
  f4 b1v = *(const f4*)&b1[i4];
  float bc = bout[SPIKE_DIM + lane];
  const int eb = wv * 8;

  for (int ee = 0; ee < 8; ++ee) {
    const int e = e0 + eb + ee;
    us4 craw = *(const us4*)&c0s[(eb+ee)*264 + i4];
    f4 c0a; c0a.x = bf2f(craw.x); c0a.y = bf2f(craw.y);
            c0a.z = bf2f(craw.z); c0a.w = bf2f(craw.w);

    unsigned long long a0 = __ballot(c0a.x >= 0.90f);
    unsigned long long a1 = __ballot(c0a.y >= 0.90f);
    unsigned long long a2 = __ballot(c0a.z >= 0.90f);
    unsigned long long a3 = __ballot(c0a.w >= 0.90f);

    f4 bnd = b1v;
    unsigned long long mm;
    #define BPROCQ(MASK, Q)                                   \
      mm = (MASK);                                            \
      while (mm) {                                            \
        int l = __builtin_ctzll(mm); mm &= mm - 1;            \
        f4 wv_ = *(const f4*)&W1T[(l*4 + (Q))*HID + i4];      \
        bnd.x += fmaxf(wv_.x, 0.f);                           \
        bnd.y += fmaxf(wv_.y, 0.f);                           \
        bnd.z += fmaxf(wv_.z, 0.f);                           \
        bnd.w += fmaxf(wv_.w, 0.f);                           \
      }
    BPROCQ(a0, 0)
    BPROCQ(a1, 1)
    BPROCQ(a2, 2)
    BPROCQ(a3, 3)
    #undef BPROCQ

    bool threat = (bnd.x >= 0.98f) | (bnd.y >= 0.98f) |
                  (bnd.z >= 0.98f) | (bnd.w >= 0.98f);

    if (__ballot(threat) == 0ull) {
      // fast path: provably no layer-1 spikes -> exact outputs
      f4 z; z.x = z.y = z.z = z.w = 0.f;
      __builtin_nontemporal_store(z, (f4*)&out[(size_t)e*HID + i4]);
      __builtin_nontemporal_store(bc,
          &out[(size_t)BATCH_N*HID + (size_t)e*COORD_DIM + lane]);
    } else {
      // ---- exact c0 recompute from global x, W0 (serial FMA, j ascending)
      float cx = 0.f, cy = 0.f, cz = 0.f, cw = 0.f;
      const float* r0 = W0 + (size_t)(i4+0)*IN_DIM;
      const float* r1 = W0 + (size_t)(i4+1)*IN_DIM;
      const float* r2 = W0 + (size_t)(i4+2)*IN_DIM;
      const float* r3 = W0 + (size_t)(i4+3)*IN_DIM;
      const float* xs_ = spk + (size_t)e*SPIKE_DIM;
      const float* xc_ = crd + (size_t)e*COORD_DIM;
      for (int j = 0; j < SPIKE_DIM; ++j) {
        float xj = xs_[j];
        cx = fmaf(xj, r0[j], cx); cy = fmaf(xj, r1[j], cy);
        cz = fmaf(xj, r2[j], cz); cw = fmaf(xj, r3[j], cw);
      }
      for (int j = 0; j < COORD_DIM; ++j) {
        float xj = xc_[j];
        cx = fmaf(xj, r0[SPIKE_DIM+j], cx); cy = fmaf(xj, r1[SPIKE_DIM+j], cy);
        cz = fmaf(xj, r2[SPIKE_DIM+j], cz); cw = fmaf(xj, r3[SPIKE_DIM+j], cw);
      }
      const float c0x = cx + b0v.x, c0y = cy + b0v.y;
      const float c0z = cz + b0v.z, c0w = cw + b0v.w;

      // ---- honest 25-step simulation (round-2 verbatim, exact)
      float v0x=0.f, v0y=0.f, v0z=0.f, v0w=0.f;
      float v1x=0.f, v1y=0.f, v1z=0.f, v1w=0.f;
      float s1x=0.f, s1y=0.f, s1z=0.f, s1w=0.f;

      for (int t = 0; t < STEPS; ++t) {
        bool sp;
        unsigned long long m0, m1, m2, m3;
        v0x = __fmul_rn(0.7f, v0x) + __fmul_rn(0.3f, c0x);
        sp = (v0x >= 1.0f); m0 = __ballot(sp); if (sp) v0x = 0.f;
        v0y = __fmul_rn(0.7f, v0y) + __fmul_rn(0.3f, c0y);
        sp = (v0y >= 1.0f); m1 = __ballot(sp); if (sp) v0y = 0.f;
        v0z = __fmul_rn(0.7f, v0z) + __fmul_rn(0.3f, c0z);
        sp = (v0z >= 1.0f); m2 = __ballot(sp); if (sp) v0z = 0.f;
        v0w = __fmul_rn(0.7f, v0w) + __fmul_rn(0.3f, c0w);
        sp = (v0w >= 1.0f); m3 = __ballot(sp); if (sp) v0w = 0.f;

        float c1x = b1v.x, c1y = b1v.y, c1z = b1v.z, c1w = b1v.w;
        f4 wcur; wcur.x = wcur.y = wcur.z = wcur.w = 0.f;
        int have = 0;
        #define PROCQ(MASK, Q)                                                  \
          mm = (MASK);                                                          \
          while (mm) {                                                          \
            int l = __builtin_ctzll(mm); mm &= mm - 1;                          \
            f4 wn = *(const f4*)&W1T[(l*4 + (Q))*HID + i4];                     \
            if (have) { c1x += wcur.x; c1y += wcur.y; c1z += wcur.z; c1w += wcur.w; } \
            wcur = wn; have = 1;                                                \
          }
        PROCQ(m0, 0)
        PROCQ(m1, 1)
        PROCQ(m2, 2)
        PROCQ(m3, 3)
        #undef PROCQ
        if (have) { c1x += wcur.x; c1y += wcur.y; c1z += wcur.z; c1w += wcur.w; }

        v1x = __fmul_rn(0.7f, v1x) + __fmul_rn(0.3f, c1x);
        sp = (v1x >= 1.0f); s1x = sp ? 1.f : 0.f; if (sp) v1x = 0.f;
        v1y = __fmul_rn(0.7f, v1y) + __fmul_rn(0.3f, c1y);
        sp = (v1y >= 1.0f); s1y = sp ? 1.f : 0.f; if (sp) v1y = 0.f;
        v1z = __fmul_rn(0.7f, v1z) + __fmul_rn(0.3f, c1z);
        sp = (v1z >= 1.0f); s1z = sp ? 1.f : 0.f; if (sp) v1z = 0.f;
        v1w = __fmul_rn(0.7f, v1w) + __fmul_rn(0.3f, c1w);
        sp = (v1w >= 1.0f); s1w = sp ? 1.f : 0.f; if (sp) v1w = 0.f;
      }

      f4 res; res.x = s1x; res.y = s1y; res.z = s1z; res.w = s1w;
      __builtin_nontemporal_store(res, (f4*)&out[(size_t)e*HID + i4]);

      unsigned long long f0 = __ballot(s1x > 0.5f);
      unsigned long long f1 = __ballot(s1y > 0.5f);
      unsigned long long f2 = __ballot(s1z > 0.5f);
      unsigned long long f3 = __ballot(s1w > 0.5f);
      float cacc = bc;
      #define CPROCQ(MASK, Q)                                 \
        mm = (MASK);                                          \
        while (mm) {                                          \
          int l = __builtin_ctzll(mm); mm &= mm - 1;          \
          cacc += WoT[(l*4 + (Q))*COORD_DIM + lane];          \
        }
      CPROCQ(f0, 0)
      CPROCQ(f1, 1)
      CPROCQ(f2, 2)
      CPROCQ(f3, 3)
      #undef CPROCQ
      __builtin_nontemporal_store(cacc,
          &out[(size_t)BATCH_N*HID + (size_t)e*COORD_DIM + lane]);
    }
  }
}

extern "C" void kernel_launch(void* const* d_in, const int* in_sizes, int n_in,
                              void* d_out, int out_size, void* d_ws, size_t ws_size,
                              hipStream_t stream) {
  (void)in_sizes; (void)n_in; (void)out_size; (void)ws_size;
  const float* spk = (const float*)d_in[0];
  const float* crd = (const float*)d_in[1];
  const float* W0  = (const float*)d_in[2];
  const float* b0  = (const float*)d_in[3];
  const float* W1  = (const float*)d_in[4];
  const float* b1  = (const float*)d_in[5];
  const float* Wo  = (const float*)d_in[6];
  const float* bo  = (const float*)d_in[7];
  float* ws  = (float*)d_ws;
  float* out = (float*)d_out;

  hipLaunchKernelGGL(prep_kernel, dim3(512), dim3(256), 0, stream, W0, W1, Wo, ws);
  hipLaunchKernelGGL(snn_kernel, dim3(BATCH_N/TILE), dim3(BLOCK), 0, stream,
                     spk, crd, W0, b0, b1, bo, ws, out);
}